// Round 9
// baseline (157.060 us; speedup 1.0000x reference)
//
#include <hip/hip_runtime.h>
#include <hip/hip_bf16.h>
#include <hip/hip_fp8.h>

#define D_DIM 768
#define B_DIM 8192
#define NT 64           // tile grid dim (8192/128)
#define NTILES 2080     // NT*(NT+1)/2 upper-triangle tiles
#define BM 128

typedef __attribute__((ext_vector_type(4))) float f32x4;
typedef __attribute__((ext_vector_type(2))) float f32x2;

// ws layout (bytes)
#define WS_XB   0                               // fp8[8192*768]    = 6,291,456
#define WS_SQ   6291456                         // float[8192]      = 32,768
#define WS_CAND 6324224                         // float[8192*64*6] = 12,582,912
#define WS_ACC  18907136                        // float[1]
#define WS_TKT  18907140                        // uint[1]

__device__ __forceinline__ void gl_lds16(const void* g, void* lds) {
  __builtin_amdgcn_global_load_lds(
      (const __attribute__((address_space(1))) unsigned int*)g,
      (__attribute__((address_space(3))) unsigned int*)lds, 16, 0, 0);
}

// branchless: maintain v[0..5] = six smallest seen, sorted ascending.
__device__ __forceinline__ void ins6(float c, float* v) {
  v[5] = fminf(v[5], c);
#pragma unroll
  for (int s = 5; s > 0; --s) {
    float lo = fminf(v[s - 1], v[s]);
    float hi = fmaxf(v[s - 1], v[s]);
    v[s - 1] = lo;
    v[s] = hi;
  }
}

// band-blocked triangle order (16x16-tile blocks, rt-major inside): L2 working
// set ~1.7 MB (fp8). g in [0,2080).
__device__ __forceinline__ void tile_decode(int g, int& rt, int& ct) {
  int base = 0;
  for (int s = 0; s < 4; ++s) {
    for (int cb = s; cb < 4; ++cb) {
      const int sz = (cb == s) ? 136 : 256;
      if (g < base + sz) {
        int loc = g - base;
        if (cb == s) {
          int r = 0;
          while (loc >= 16 - r) {
            loc -= 16 - r;
            ++r;
          }
          rt = s * 16 + r;
          ct = cb * 16 + r + loc;
        } else {
          rt = s * 16 + (loc >> 4);
          ct = cb * 16 + (loc & 15);
        }
        return;
      }
      base += sz;
    }
  }
  rt = 0;
  ct = 0;
}

// kernel 1: cast fp32 -> fp8 e4m3 (OCP), row sum-of-squares of the DECODED fp8
// values (so self-distance rsq+rsq-2*G(i,i) stays ~0).
__global__ __launch_bounds__(256) void cast_sq_kernel(
    const float* __restrict__ x, unsigned char* __restrict__ xb,
    float* __restrict__ sq, float* __restrict__ acc,
    unsigned int* __restrict__ tkt) {
  const int t = threadIdx.x;
  const int w = t >> 6, lane = t & 63;
  const int row = blockIdx.x * 4 + w;
  if (blockIdx.x == 0) {
    if (t == 0) acc[0] = 0.0f;
    if (t == 1) tkt[0] = 0u;
  }
  const f32x4* xr = (const f32x4*)(x + (size_t)row * D_DIM);
  unsigned int* xbr = (unsigned int*)(xb + (size_t)row * D_DIM);
  float s = 0.0f;
#pragma unroll
  for (int c = 0; c < 3; ++c) {
    const int idx = c * 64 + lane;
    f32x4 v = xr[idx];
    unsigned int p = 0;
#pragma unroll
    for (int e = 0; e < 4; ++e) {
      __hip_fp8_e4m3 h(v[e]);
      const float d = (float)h;
      s += d * d;
      p |= ((unsigned int)h.__x) << (8 * e);
    }
    xbr[idx] = p;
  }
#pragma unroll
  for (int off = 32; off > 0; off >>= 1) s += __shfl_down(s, off, 64);
  if (lane == 0) sq[row] = s;
}

// ------- kernel 2: fp8 symmetric 128x128 tiles, ring-of-4, 4 blocks/CU -------
// Round-8 skeleton (proven), fp8 data: fragments 8 B/lane (ds_read_b64),
// staging 32 B/row/section -> LDS pipe bytes per block-section 48->24 KB (the
// measured binding pipe). Ring-of-4 4KB slots (32 KB < epilogue's 34 KB: free).
// One gl_lds per operand per thread per section (thread t -> row t>>1, 16B half
// t&1). Counted vmcnt: 2 loads/section, lead-3 -> VMW(4) steady, drain 4/2/0.
// b64 frag reads are bank-uniform (4/bank = b64 floor) with the linear layout.
#define ASL(s) ((s) * 8192)
#define BSL(s) ((s) * 8192 + 4096)
#define VMW(N) asm volatile("s_waitcnt vmcnt(" #N ")" ::: "memory")
#define BAR()                         \
  {                                   \
    asm volatile("" ::: "memory");    \
    __builtin_amdgcn_s_barrier();     \
    asm volatile("" ::: "memory");    \
  }

__global__ __launch_bounds__(256, 4) void knn_gemm_kernel(
    const unsigned char* __restrict__ xb, const float* __restrict__ sq,
    float* __restrict__ cand) {
  __shared__ __align__(16) char smem[34048];
  const int t = threadIdx.x;
  const int lane = t & 63, w = t >> 6;
  const int wm = w >> 1, wn = w & 1;  // 2x2 wave grid; wave tile 64x64
  const int quad = lane >> 4, m16 = lane & 15;

  // XCD chunking (2080 = 8*260, bijective) + band-blocked decode
  const int g = (blockIdx.x & 7) * (NTILES / 8) + (blockIdx.x >> 3);
  int rt, ct;
  tile_decode(g, rt, ct);
  const bool offdiag = (ct > rt);
  const int rowBase = rt * BM, colBase = ct * BM;

  // staging: thread t -> slot row t>>1, 16B half t&1 (linear, no swizzle)
  const unsigned char* pA =
      xb + (size_t)(rowBase + (t >> 1)) * D_DIM + (t & 1) * 16;
  const unsigned char* pB =
      xb + (size_t)(colBase + (t >> 1)) * D_DIM + (t & 1) * 16;

  // fragment read base: row R = ws*64 + i*16 + m16 -> byte R*32 + quad*8
  const int aBase = wm * 2048 + m16 * 32 + quad * 8;
  const int bBase = wn * 2048 + m16 * 32 + quad * 8;

  float rsq[16];
#pragma unroll
  for (int i = 0; i < 4; ++i)
#pragma unroll
    for (int r = 0; r < 4; ++r)
      rsq[i * 4 + r] = sq[rowBase + wm * 64 + i * 16 + quad * 4 + r];
  float csq[4];
#pragma unroll
  for (int j = 0; j < 4; ++j) csq[j] = sq[colBase + wn * 64 + j * 16 + m16];

  f32x4 acv[4][4];
  const f32x4 zero = {0.0f, 0.0f, 0.0f, 0.0f};
#pragma unroll
  for (int i = 0; i < 4; ++i)
#pragma unroll
    for (int j = 0; j < 4; ++j) acv[i][j] = zero;

#define STAGE(P, KOFF, REGION) gl_lds16((P) + (KOFF), smem + (REGION) + t * 16)

  long aF[4], bF[4];
#define LDA(BASE)                                                        \
  {                                                                      \
    _Pragma("unroll") for (int ii = 0; ii < 4; ++ii)                     \
        aF[ii] = *(const long*)(smem + (BASE) + aBase + ii * 512);       \
  }
#define LDB(BASE)                                                        \
  {                                                                      \
    _Pragma("unroll") for (int j = 0; j < 4; ++j)                        \
        bF[j] = *(const long*)(smem + (BASE) + bBase + j * 512);         \
  }
#define MFMA16                                                           \
  {                                                                      \
    __builtin_amdgcn_s_setprio(1);                                       \
    _Pragma("unroll") for (int ii = 0; ii < 4; ++ii)                     \
        _Pragma("unroll") for (int j = 0; j < 4; ++j)                    \
            acv[ii][j] = __builtin_amdgcn_mfma_f32_16x16x32_fp8_fp8(     \
                aF[ii], bF[j], acv[ii][j], 0, 0, 0);                     \
    __builtin_amdgcn_s_setprio(0);                                       \
  }

  // prologue: sections 0..2 -> slots 0..2 (6 loads in flight)
  STAGE(pA, 0, ASL(0));
  STAGE(pB, 0, BSL(0));
  STAGE(pA, 32, ASL(1));
  STAGE(pB, 32, BSL(1));
  STAGE(pA, 64, ASL(2));
  STAGE(pB, 64, BSL(2));

  // sections 0..19: consume slot s&3, stage s+3 into slot (s+3)&3 (= the slot
  // consumed at s-1; its ds_reads retired before this barrier)
  for (int a = 0; a < 5; ++a) {
#pragma unroll
    for (int i = 0; i < 4; ++i) {
      const int s = a * 4 + i;
      VMW(4);
      BAR();
      STAGE(pA, (s + 3) * 32, ASL((i + 3) & 3));
      STAGE(pB, (s + 3) * 32, BSL((i + 3) & 3));
      LDA(ASL(i));
      LDB(BSL(i));
      MFMA16;
    }
  }
  // s20 (slot 0), stages s23 -> slot 3
  VMW(4);
  BAR();
  STAGE(pA, 23 * 32, ASL(3));
  STAGE(pB, 23 * 32, BSL(3));
  LDA(ASL(0));
  LDB(BSL(0));
  MFMA16;
  // s21..s23: counted drain
  VMW(4);
  BAR();
  LDA(ASL(1));
  LDB(BSL(1));
  MFMA16;
  VMW(2);
  BAR();
  LDA(ASL(2));
  LDB(BSL(2));
  MFMA16;
  VMW(0);
  BAR();
  LDA(ASL(3));
  LDB(BSL(3));
  MFMA16;

  // ---------------- epilogue: 2 groups of 64 rows, split row/col duty ----------------
  float* distS = (float*)smem;             // [64][132] f32 = 33792 B
  float* rsqS = (float*)(smem + 33792);    // [64] f32
  float colrun[6];
#pragma unroll
  for (int q = 0; q < 6; ++q) colrun[q] = 1e30f;

#pragma unroll
  for (int gg = 0; gg < 2; ++gg) {
    BAR();
    if (wm == gg) {
      // row-key = csq[col] - 2G (row-constant rsq added at write; order-invariant)
#pragma unroll
      for (int ii = 0; ii < 4; ++ii)
#pragma unroll
        for (int j = 0; j < 4; ++j)
#pragma unroll
          for (int r = 0; r < 4; ++r)
            distS[(ii * 16 + quad * 4 + r) * 132 + wn * 64 + j * 16 + m16] =
                csq[j] - 2.0f * acv[ii][j][r];
      if (wn == 0 && m16 == 0) {
#pragma unroll
        for (int ii = 0; ii < 4; ++ii)
#pragma unroll
          for (int r = 0; r < 4; ++r)
            rsqS[ii * 16 + quad * 4 + r] = rsq[ii * 4 + r];
      }
    }
    BAR();
    if (t < 128) {
      // row-side: 2 thr/row x 64 cols, single shfl merge with partner t^1
      const int row_l = t >> 1, half = t & 1;
      const float* drow = distS + row_l * 132 + half * 64;
      float v[6];
#pragma unroll
      for (int q = 0; q < 6; ++q) v[q] = 1e30f;
#pragma unroll
      for (int k = 0; k < 16; ++k) {
        f32x4 dv = *(const f32x4*)(drow + k * 4);
        ins6(dv[0], v);
        ins6(dv[1], v);
        ins6(dv[2], v);
        ins6(dv[3], v);
      }
      float o[6];
#pragma unroll
      for (int q = 0; q < 6; ++q) o[q] = __shfl_xor(v[q], 1, 64);
#pragma unroll
      for (int q = 0; q < 6; ++q) ins6(o[q], v);
      if (half == 0) {
        const int grow = rowBase + gg * 64 + row_l;
        const float rq = rsqS[row_l];
        float* o6 = cand + (size_t)(grow * NT + ct) * 6;
        f32x2 w0 = {fmaxf(v[0] + rq, 0.0f), fmaxf(v[1] + rq, 0.0f)};
        f32x2 w1 = {fmaxf(v[2] + rq, 0.0f), fmaxf(v[3] + rq, 0.0f)};
        f32x2 w2 = {fmaxf(v[4] + rq, 0.0f), fmaxf(v[5] + rq, 0.0f)};
        *(f32x2*)o6 = w0;
        *(f32x2*)(o6 + 2) = w1;
        *(f32x2*)(o6 + 4) = w2;
      }
    } else if (offdiag) {
      // col-side: 1 thr/col; key = distS + rsq[row] = full d^2.
      const int col = t - 128;
#pragma unroll
      for (int r = 0; r < 64; ++r) ins6(distS[r * 132 + col] + rsqS[r], colrun);
    }
  }
  if (offdiag && t >= 128) {
    const int colg = colBase + (t - 128);
    float* o6 = cand + (size_t)(colg * NT + rt) * 6;
    f32x2 w0 = {fmaxf(colrun[0], 0.0f), fmaxf(colrun[1], 0.0f)};
    f32x2 w1 = {fmaxf(colrun[2], 0.0f), fmaxf(colrun[3], 0.0f)};
    f32x2 w2 = {fmaxf(colrun[4], 0.0f), fmaxf(colrun[5], 0.0f)};
    *(f32x2*)o6 = w0;
    *(f32x2*)(o6 + 2) = w1;
    *(f32x2*)(o6 + 4) = w2;
  }
}

// kernel 3: per-row merge of 64 chunk-candidates -> sqrt -> log -> global sum,
// with fused finalize via ticket (last block writes the output).
__global__ __launch_bounds__(256) void knn_merge_kernel(
    const float* __restrict__ cand, float* __restrict__ acc,
    unsigned int* __restrict__ tkt, float* __restrict__ out) {
  const int t = threadIdx.x;
  const int r = blockIdx.x * 32 + (t >> 3);
  const float* cr = cand + (size_t)r * (NT * 6) + (size_t)(t & 7) * 48;
  float v[6];
#pragma unroll
  for (int s = 0; s < 6; ++s) v[s] = 1e30f;
#pragma unroll
  for (int c = 0; c < 12; ++c) {
    f32x4 dv = *(const f32x4*)(cr + c * 4);
    ins6(dv[0], v);
    ins6(dv[1], v);
    ins6(dv[2], v);
    ins6(dv[3], v);
  }
#pragma unroll
  for (int st = 1; st <= 4; st <<= 1) {
    float o[6];
#pragma unroll
    for (int q = 0; q < 6; ++q) o[q] = __shfl_xor(v[q], st, 64);
#pragma unroll
    for (int q = 0; q < 6; ++q) ins6(o[q], v);
  }
  float term = 0.0f;
  if ((t & 7) == 0) {
    // v sorted ascending on d^2: v[0] = self (~0); knn_mean = mean of sqrt(v[1..5])
    const float mean =
        (sqrtf(v[1]) + sqrtf(v[2]) + sqrtf(v[3]) + sqrtf(v[4]) + sqrtf(v[5])) * 0.2f;
    term = logf(mean + 1e-8f);
  }
#pragma unroll
  for (int off = 32; off > 0; off >>= 1) term += __shfl_down(term, off, 64);
  __shared__ float red[4];
  if ((t & 63) == 0) red[t >> 6] = term;
  __syncthreads();
  if (t == 0) {
    atomicAdd(acc, red[0] + red[1] + red[2] + red[3]);
    __threadfence();
    const unsigned int tk = atomicAdd(tkt, 1u);
    if (tk == (B_DIM / 32) - 1) {
      const float total = atomicAdd(acc, 0.0f);  // coherent read of final sum
      out[0] = -total * (1.0f / 8192.0f);
    }
  }
}

extern "C" void kernel_launch(void* const* d_in, const int* in_sizes, int n_in,
                              void* d_out, int out_size, void* d_ws, size_t ws_size,
                              hipStream_t stream) {
  const float* x = (const float*)d_in[0];
  float* out = (float*)d_out;
  char* ws = (char*)d_ws;
  unsigned char* xb = (unsigned char*)(ws + WS_XB);
  float* sq = (float*)(ws + WS_SQ);
  float* cand = (float*)(ws + WS_CAND);
  float* acc = (float*)(ws + WS_ACC);
  unsigned int* tkt = (unsigned int*)(ws + WS_TKT);

  cast_sq_kernel<<<B_DIM / 4, 256, 0, stream>>>(x, xb, sq, acc, tkt);
  knn_gemm_kernel<<<NTILES, 256, 0, stream>>>(xb, sq, cand);
  knn_merge_kernel<<<B_DIM / 32, 256, 0, stream>>>(cand, acc, tkt, out);
}

// Round 10
// 141.548 us; speedup vs baseline: 1.1096x; 1.1096x over previous
//
#include <hip/hip_runtime.h>
#include <hip/hip_bf16.h>
#include <hip/hip_fp8.h>

#define D_DIM 768
#define B_DIM 8192
#define NT 64           // tile grid dim (8192/128)
#define NTILES 2080     // NT*(NT+1)/2 upper-triangle tiles
#define BM 128

typedef __attribute__((ext_vector_type(4))) float f32x4;
typedef __attribute__((ext_vector_type(2))) float f32x2;
typedef __attribute__((ext_vector_type(4))) int i32x4;
typedef __attribute__((ext_vector_type(8))) int i32x8;

// ws layout (bytes)
#define WS_XB   0                               // fp8[8192*768]    = 6,291,456
#define WS_SQ   6291456                         // float[8192]      = 32,768
#define WS_CAND 6324224                         // float[8192*64*6] = 12,582,912
#define WS_ACC  18907136                        // float[1]
#define WS_TKT  18907140                        // uint[1]

__device__ __forceinline__ void gl_lds16(const void* g, void* lds) {
  __builtin_amdgcn_global_load_lds(
      (const __attribute__((address_space(1))) unsigned int*)g,
      (__attribute__((address_space(3))) unsigned int*)lds, 16, 0, 0);
}

// branchless: maintain v[0..5] = six smallest seen, sorted ascending.
__device__ __forceinline__ void ins6(float c, float* v) {
  v[5] = fminf(v[5], c);
#pragma unroll
  for (int s = 5; s > 0; --s) {
    float lo = fminf(v[s - 1], v[s]);
    float hi = fmaxf(v[s - 1], v[s]);
    v[s - 1] = lo;
    v[s] = hi;
  }
}

// band-blocked triangle order (16x16-tile blocks, rt-major inside). g in [0,2080).
__device__ __forceinline__ void tile_decode(int g, int& rt, int& ct) {
  int base = 0;
  for (int s = 0; s < 4; ++s) {
    for (int cb = s; cb < 4; ++cb) {
      const int sz = (cb == s) ? 136 : 256;
      if (g < base + sz) {
        int loc = g - base;
        if (cb == s) {
          int r = 0;
          while (loc >= 16 - r) {
            loc -= 16 - r;
            ++r;
          }
          rt = s * 16 + r;
          ct = cb * 16 + r + loc;
        } else {
          rt = s * 16 + (loc >> 4);
          ct = cb * 16 + (loc & 15);
        }
        return;
      }
      base += sz;
    }
  }
  rt = 0;
  ct = 0;
}

// kernel 1: cast fp32 -> fp8 e4m3 (OCP), row sum-of-squares of the DECODED fp8
// values (so self-distance rsq+rsq-2*G(i,i) stays ~0). Verified round 9.
__global__ __launch_bounds__(256) void cast_sq_kernel(
    const float* __restrict__ x, unsigned char* __restrict__ xb,
    float* __restrict__ sq, float* __restrict__ acc,
    unsigned int* __restrict__ tkt) {
  const int t = threadIdx.x;
  const int w = t >> 6, lane = t & 63;
  const int row = blockIdx.x * 4 + w;
  if (blockIdx.x == 0) {
    if (t == 0) acc[0] = 0.0f;
    if (t == 1) tkt[0] = 0u;
  }
  const f32x4* xr = (const f32x4*)(x + (size_t)row * D_DIM);
  unsigned int* xbr = (unsigned int*)(xb + (size_t)row * D_DIM);
  float s = 0.0f;
#pragma unroll
  for (int c = 0; c < 3; ++c) {
    const int idx = c * 64 + lane;
    f32x4 v = xr[idx];
    unsigned int p = 0;
#pragma unroll
    for (int e = 0; e < 4; ++e) {
      __hip_fp8_e4m3 h(v[e]);
      const float d = (float)h;
      s += d * d;
      p |= ((unsigned int)h.__x) << (8 * e);
    }
    xbr[idx] = p;
  }
#pragma unroll
  for (int off = 32; off > 0; off >>= 1) s += __shfl_down(s, off, 64);
  if (lane == 0) sq[row] = s;
}

// ------- kernel 2: MX-fp8 K=128 sections, symmetric 128x128 tiles, dbuf -------
// 6 sections of K=128 (vs 24 of K=32): 96 scaled MFMAs/wave (2x flop rate),
// 12 barrier-pairs, b128 frag reads. Scales pinned to 1.0 (0x7F E8M0) -> exact
// fp8 semantics (round-9 verified numerics).
// LDS slot swizzle (conflict-free b128): within a row's 8x16B slots,
//   slot(q,h,row) = ((q+row)&3)*2 + ((h+(row>>2))&1)
// -> 8 lanes per 16B slot = the b128 floor. gl_lds keeps LDS linear; the
// inverse permutation is applied to the per-thread GLOBAL source offset.
// Double-buffer 2 x (16KB A + 16KB B) = 64 KiB -> 2 blocks/CU.
// vmcnt: stage(s+1) issued first, then VMW(8) drains exactly stage(s);
// VMW(0) only at the last section.
#define ABUF(b) ((b) * 32768)
#define BBUF(b) ((b) * 32768 + 16384)
#define VMW(N) asm volatile("s_waitcnt vmcnt(" #N ")" ::: "memory")
#define BAR()                         \
  {                                   \
    asm volatile("" ::: "memory");    \
    __builtin_amdgcn_s_barrier();     \
    asm volatile("" ::: "memory");    \
  }

__global__ __launch_bounds__(256, 2) void knn_gemm_kernel(
    const unsigned char* __restrict__ xb, const float* __restrict__ sq,
    float* __restrict__ cand) {
  __shared__ __align__(16) char smem[65536];
  const int t = threadIdx.x;
  const int lane = t & 63, w = t >> 6;
  const int wm = w >> 1, wn = w & 1;  // 2x2 wave grid; wave tile 64x64
  const int quad = lane >> 4, m16 = lane & 15;

  // XCD chunking (2080 = 8*260, bijective) + band-blocked decode
  const int g = (blockIdx.x & 7) * (NTILES / 8) + (blockIdx.x >> 3);
  int rt, ct;
  tile_decode(g, rt, ct);
  const bool offdiag = (ct > rt);
  const int rowBase = rt * BM, colBase = ct * BM;

  // staging: thread t covers rows (t>>3)+32q, slot t&7; inverse slot swizzle on
  // the global source. (row&3) and ((row>>2)&1) are invariant under row+=32.
  const int sR = t >> 3, sS = t & 7;
  const int q_src = ((sS >> 1) - sR) & 3;
  const int h_src = ((sS & 1) - (sR >> 2)) & 1;
  const int srcOff = q_src * 32 + h_src * 16;
  const unsigned char* pA = xb + (size_t)(rowBase + sR) * D_DIM + srcOff;
  const unsigned char* pB = xb + (size_t)(colBase + sR) * D_DIM + srcOff;

  // fragment read offsets (within a row's 128 B): pair = (quad+m16)&3,
  // bit = (m16>>2)&1; lo slot byte = pair*32 + bit*16, hi = pair*32 + (bit^1)*16
  const int pairOff = ((quad + m16) & 3) * 32;
  const int bitOff = ((m16 >> 2) & 1) * 16;
  const int laneLo = m16 * 128 + pairOff + bitOff;
  const int laneHi = m16 * 128 + pairOff + (bitOff ^ 16);
  const int aRow = wm * 8192;  // row stride 128 B, 64 rows per wave-half
  const int bRow = wn * 8192;

  float rsq[16];
#pragma unroll
  for (int i = 0; i < 4; ++i)
#pragma unroll
    for (int r = 0; r < 4; ++r)
      rsq[i * 4 + r] = sq[rowBase + wm * 64 + i * 16 + quad * 4 + r];
  float csq[4];
#pragma unroll
  for (int j = 0; j < 4; ++j) csq[j] = sq[colBase + wn * 64 + j * 16 + m16];

  f32x4 acv[4][4];
  const f32x4 zero = {0.0f, 0.0f, 0.0f, 0.0f};
#pragma unroll
  for (int i = 0; i < 4; ++i)
#pragma unroll
    for (int j = 0; j < 4; ++j) acv[i][j] = zero;

#define STAGE(P, KOFF, REGION)                                          \
  {                                                                     \
    _Pragma("unroll") for (int q = 0; q < 4; ++q)                       \
        gl_lds16((P) + (KOFF) + q * 32 * D_DIM,                         \
                 smem + (REGION) + q * 4096 + t * 16);                  \
  }

  i32x8 aF[4], bF[4];
#define LDA(BASE)                                                            \
  {                                                                          \
    _Pragma("unroll") for (int ii = 0; ii < 4; ++ii) {                       \
      i32x4 lo = *(const i32x4*)(smem + (BASE) + aRow + ii * 2048 + laneLo); \
      i32x4 hi = *(const i32x4*)(smem + (BASE) + aRow + ii * 2048 + laneHi); \
      __builtin_memcpy(&aF[ii], &lo, 16);                                    \
      __builtin_memcpy(((char*)&aF[ii]) + 16, &hi, 16);                      \
    }                                                                        \
  }
#define LDB(BASE)                                                            \
  {                                                                          \
    _Pragma("unroll") for (int j = 0; j < 4; ++j) {                          \
      i32x4 lo = *(const i32x4*)(smem + (BASE) + bRow + j * 2048 + laneLo);  \
      i32x4 hi = *(const i32x4*)(smem + (BASE) + bRow + j * 2048 + laneHi);  \
      __builtin_memcpy(&bF[j], &lo, 16);                                     \
      __builtin_memcpy(((char*)&bF[j]) + 16, &hi, 16);                       \
    }                                                                        \
  }
#define MFMAS16                                                              \
  {                                                                          \
    __builtin_amdgcn_s_setprio(1);                                           \
    _Pragma("unroll") for (int ii = 0; ii < 4; ++ii)                         \
        _Pragma("unroll") for (int j = 0; j < 4; ++j)                        \
            acv[ii][j] = __builtin_amdgcn_mfma_scale_f32_16x16x128_f8f6f4(   \
                aF[ii], bF[j], acv[ii][j], 0, 0, 0, 0x7F7F7F7F, 0,           \
                0x7F7F7F7F);                                                 \
    __builtin_amdgcn_s_setprio(0);                                           \
  }

  // prologue: section 0 -> buffer 0 (8 loads)
  STAGE(pA, 0, ABUF(0));
  STAGE(pB, 0, BBUF(0));

#pragma unroll
  for (int s = 0; s < 6; ++s) {
    const int b = s & 1;
    if (s < 5) {
      STAGE(pA, (s + 1) * 128, ABUF(b ^ 1));
      STAGE(pB, (s + 1) * 128, BBUF(b ^ 1));
    }
    if (s < 5) {
      VMW(8);
    } else {
      VMW(0);
    }
    BAR();
    LDA(ABUF(b));
    LDB(BBUF(b));
    MFMAS16;
    BAR();
  }

  // ---------------- epilogue: 2 groups of 64 rows, split row/col duty ----------------
  float* distS = (float*)smem;             // [64][132] f32 = 33792 B
  float* rsqS = (float*)(smem + 33792);    // [64] f32
  float colrun[6];
#pragma unroll
  for (int q = 0; q < 6; ++q) colrun[q] = 1e30f;

#pragma unroll
  for (int gg = 0; gg < 2; ++gg) {
    BAR();
    if (wm == gg) {
      // row-key = csq[col] - 2G (row-constant rsq added at write; order-invariant)
#pragma unroll
      for (int ii = 0; ii < 4; ++ii)
#pragma unroll
        for (int j = 0; j < 4; ++j)
#pragma unroll
          for (int r = 0; r < 4; ++r)
            distS[(ii * 16 + quad * 4 + r) * 132 + wn * 64 + j * 16 + m16] =
                csq[j] - 2.0f * acv[ii][j][r];
      if (wn == 0 && m16 == 0) {
#pragma unroll
        for (int ii = 0; ii < 4; ++ii)
#pragma unroll
          for (int r = 0; r < 4; ++r)
            rsqS[ii * 16 + quad * 4 + r] = rsq[ii * 4 + r];
      }
    }
    BAR();
    if (t < 128) {
      // row-side: 2 thr/row x 64 cols, single shfl merge with partner t^1
      const int row_l = t >> 1, half = t & 1;
      const float* drow = distS + row_l * 132 + half * 64;
      float v[6];
#pragma unroll
      for (int q = 0; q < 6; ++q) v[q] = 1e30f;
#pragma unroll
      for (int k = 0; k < 16; ++k) {
        f32x4 dv = *(const f32x4*)(drow + k * 4);
        ins6(dv[0], v);
        ins6(dv[1], v);
        ins6(dv[2], v);
        ins6(dv[3], v);
      }
      float o[6];
#pragma unroll
      for (int q = 0; q < 6; ++q) o[q] = __shfl_xor(v[q], 1, 64);
#pragma unroll
      for (int q = 0; q < 6; ++q) ins6(o[q], v);
      if (half == 0) {
        const int grow = rowBase + gg * 64 + row_l;
        const float rq = rsqS[row_l];
        float* o6 = cand + (size_t)(grow * NT + ct) * 6;
        f32x2 w0 = {fmaxf(v[0] + rq, 0.0f), fmaxf(v[1] + rq, 0.0f)};
        f32x2 w1 = {fmaxf(v[2] + rq, 0.0f), fmaxf(v[3] + rq, 0.0f)};
        f32x2 w2 = {fmaxf(v[4] + rq, 0.0f), fmaxf(v[5] + rq, 0.0f)};
        *(f32x2*)o6 = w0;
        *(f32x2*)(o6 + 2) = w1;
        *(f32x2*)(o6 + 4) = w2;
      }
    } else if (offdiag) {
      // col-side: 1 thr/col; key = distS + rsq[row] = full d^2.
      const int col = t - 128;
#pragma unroll
      for (int r = 0; r < 64; ++r) ins6(distS[r * 132 + col] + rsqS[r], colrun);
    }
  }
  if (offdiag && t >= 128) {
    const int colg = colBase + (t - 128);
    float* o6 = cand + (size_t)(colg * NT + rt) * 6;
    f32x2 w0 = {fmaxf(colrun[0], 0.0f), fmaxf(colrun[1], 0.0f)};
    f32x2 w1 = {fmaxf(colrun[2], 0.0f), fmaxf(colrun[3], 0.0f)};
    f32x2 w2 = {fmaxf(colrun[4], 0.0f), fmaxf(colrun[5], 0.0f)};
    *(f32x2*)o6 = w0;
    *(f32x2*)(o6 + 2) = w1;
    *(f32x2*)(o6 + 4) = w2;
  }
}

// kernel 3: per-row merge of 64 chunk-candidates -> sqrt -> log -> global sum,
// with fused finalize via ticket (last block writes the output).
__global__ __launch_bounds__(256) void knn_merge_kernel(
    const float* __restrict__ cand, float* __restrict__ acc,
    unsigned int* __restrict__ tkt, float* __restrict__ out) {
  const int t = threadIdx.x;
  const int r = blockIdx.x * 32 + (t >> 3);
  const float* cr = cand + (size_t)r * (NT * 6) + (size_t)(t & 7) * 48;
  float v[6];
#pragma unroll
  for (int s = 0; s < 6; ++s) v[s] = 1e30f;
#pragma unroll
  for (int c = 0; c < 12; ++c) {
    f32x4 dv = *(const f32x4*)(cr + c * 4);
    ins6(dv[0], v);
    ins6(dv[1], v);
    ins6(dv[2], v);
    ins6(dv[3], v);
  }
#pragma unroll
  for (int st = 1; st <= 4; st <<= 1) {
    float o[6];
#pragma unroll
    for (int q = 0; q < 6; ++q) o[q] = __shfl_xor(v[q], st, 64);
#pragma unroll
    for (int q = 0; q < 6; ++q) ins6(o[q], v);
  }
  float term = 0.0f;
  if ((t & 7) == 0) {
    // v sorted ascending on d^2: v[0] = self (~0); knn_mean = mean of sqrt(v[1..5])
    const float mean =
        (sqrtf(v[1]) + sqrtf(v[2]) + sqrtf(v[3]) + sqrtf(v[4]) + sqrtf(v[5])) * 0.2f;
    term = logf(mean + 1e-8f);
  }
#pragma unroll
  for (int off = 32; off > 0; off >>= 1) term += __shfl_down(term, off, 64);
  __shared__ float red[4];
  if ((t & 63) == 0) red[t >> 6] = term;
  __syncthreads();
  if (t == 0) {
    atomicAdd(acc, red[0] + red[1] + red[2] + red[3]);
    __threadfence();
    const unsigned int tk = atomicAdd(tkt, 1u);
    if (tk == (B_DIM / 32) - 1) {
      const float total = atomicAdd(acc, 0.0f);  // coherent read of final sum
      out[0] = -total * (1.0f / 8192.0f);
    }
  }
}

extern "C" void kernel_launch(void* const* d_in, const int* in_sizes, int n_in,
                              void* d_out, int out_size, void* d_ws, size_t ws_size,
                              hipStream_t stream) {
  const float* x = (const float*)d_in[0];
  float* out = (float*)d_out;
  char* ws = (char*)d_ws;
  unsigned char* xb = (unsigned char*)(ws + WS_XB);
  float* sq = (float*)(ws + WS_SQ);
  float* cand = (float*)(ws + WS_CAND);
  float* acc = (float*)(ws + WS_ACC);
  unsigned int* tkt = (unsigned int*)(ws + WS_TKT);

  cast_sq_kernel<<<B_DIM / 4, 256, 0, stream>>>(x, xb, sq, acc, tkt);
  knn_gemm_kernel<<<NTILES, 256, 0, stream>>>(xb, sq, cand);
  knn_merge_kernel<<<B_DIM / 32, 256, 0, stream>>>(cand, acc, tkt, out);
}